// Round 23
// baseline (53.074 us; speedup 1.0000x reference)
//
#include <hip/hip_runtime.h>
#include <math.h>

#define INDIM 10
#define DIM 32
#define LAYERS 4
#define MODES 17
#define NT 2

#define LOG2E 1.4426950408889634f
#define LN2   0.6931471805599453f

// d_ws layout:
//   [0, 11264)        : frag f16 [11][64][8]  (16x16 A-operand fragments)
//   [11264, 12032)    : bias2 f32 [6][32]     (compact per-stage bias tables)
#define WS_FRAG_OFF 0
#define WS_BIAS_OFF 11264

typedef _Float16 f16;
typedef _Float16 f16x8 __attribute__((ext_vector_type(8)));
typedef float f32x4v __attribute__((ext_vector_type(4)));
typedef unsigned u32x2 __attribute__((ext_vector_type(2)));

union BU { f16x8 v; unsigned u[4]; };

// ---------------------------------------------------------------------------
// FUSED 2-phase prep (R16-verified), 16x16 fragments (R17-verified layouts).
// ---------------------------------------------------------------------------
__global__ void fno_prep(const float* __restrict__ wr,
                         const float* __restrict__ wi,
                         const float* __restrict__ projW,
                         const float* __restrict__ stemW,
                         const float* __restrict__ headW,
                         const float* __restrict__ stemB,
                         const float* __restrict__ projB,
                         const float* __restrict__ headB,
                         f16* __restrict__ frag,
                         float* __restrict__ bias2) {
    const int l  = blockIdx.x;
    const int tx = threadIdx.x;
    const int j  = tx & 31;   // output feat
    const int n  = tx >> 5;   // input feat (k)

    __shared__ float ct[32], st[32];
    __shared__ float sre[MODES][32], sim[MODES][32];
    if (tx < 32) {
        float ang = (2.0f * 3.14159265358979323846f / 32.0f) * (float)tx;
        ct[tx] = cosf(ang);
        st[tx] = sinf(ang);
    }
    __syncthreads();

    const float* lwr = wr + l * MODES * MODES;
    const float* lwi = wi + l * MODES * MODES;

    // phase 1: y_o(n) once per (o,n)
    if (tx < MODES * 32) {
        const int o  = tx >> 5;
        const int nn = tx & 31;
        float re = 0.0f, im = 0.0f;
        for (int m = 0; m < MODES; ++m) {
            int t = (m * nn) & 31;
            float c = ct[t], s = st[t];
            float a = lwr[m * MODES + o];
            float b = lwi[m * MODES + o];
            re += c * a + s * b;
            im += c * b - s * a;
        }
        sre[o][nn] = re;
        sim[o][nn] = im;
    }
    __syncthreads();

    // phase 2: o-sum from LDS broadcast
    float acc = 0.0f;
    for (int o = 0; o < MODES; ++o) {
        int t2 = (o * j) & 31;
        float f = (o == 0 || o == 16) ? 1.0f : 2.0f;
        acc += f * (sre[o][n] * ct[t2] - sim[o][n] * st[t2]);
    }
    acc = acc * (1.0f / 32.0f) + projW[(l * DIM + n) * DIM + j];

    const float wscale = (l == 0) ? LOG2E : 1.0f;
    // 16x16 A-frag mapping: f=2l+(j>>4), lane=16*(n>>3)+(j&15), e=n&7
    const int h  = j >> 4;
    const int ln = 16 * (n >> 3) + (j & 15);
    const int e  = n & 7;
    frag[((l * 2 + h) * 64 + ln) * 8 + e] = (f16)(wscale * acc);

    if (l == 0) {
        if (tx < 64) {
            const int lnn = tx;
            const int c2  = lnn & 15;
            const int g2  = lnn >> 4;
#pragma unroll
            for (int hh = 0; hh < 2; ++hh)
#pragma unroll
                for (int ee = 0; ee < 8; ++ee) {
                    int k = 8 * g2 + ee;
                    frag[((8 + hh) * 64 + lnn) * 8 + ee] =
                        (f16)(k < INDIM ? stemW[k * DIM + 16 * hh + c2] : 0.0f);
                }
#pragma unroll
            for (int ee = 0; ee < 8; ++ee) {
                int k = 8 * g2 + ee;
                frag[(10 * 64 + lnn) * 8 + ee] =
                    (f16)(c2 < INDIM ? LN2 * headW[k * INDIM + c2] : 0.0f);
            }
        }
        if (tx < 32) {
#pragma unroll
            for (int f = 0; f < 6; ++f) {
                float v;
                if (f == 0)      v = stemB[tx];
                else if (f <= 4) v = LOG2E * projB[(f - 1) * DIM + tx];
                else             v = (tx < INDIM) ? headB[tx] : 0.0f;
                bias2[f * 32 + tx] = v;
            }
        }
    }
}

__device__ __forceinline__ float exp2_fast(float x) {
#if __has_builtin(__builtin_amdgcn_exp2f)
    return __builtin_amdgcn_exp2f(x);
#else
    return exp2f(x);
#endif
}

__device__ __forceinline__ unsigned pk2(float a, float b) {
    auto h2 = __builtin_amdgcn_cvt_pkrtz(a, b);
    return __builtin_bit_cast(unsigned, h2);
}

// lane<32 <-> lane>=32 exchange (R8-verified builtin path).
__device__ __forceinline__ void pswap32(unsigned& a, unsigned& b) {
#if __has_builtin(__builtin_amdgcn_permlane32_swap)
    u32x2 r = __builtin_amdgcn_permlane32_swap(a, b, false, false);
    a = r[0];
    b = r[1];
#else
    asm("v_permlane32_swap_b32 %0, %1" : "+v"(a), "+v"(b));
    __builtin_amdgcn_sched_barrier(0);
#endif
}

// lane<->lane^16 exchange within each 32-half (R17-verified correct).
__device__ __forceinline__ void pswap16(unsigned& a, unsigned& b) {
#if __has_builtin(__builtin_amdgcn_permlane16_swap)
    u32x2 r = __builtin_amdgcn_permlane16_swap(a, b, false, false);
    a = r[0];
    b = r[1];
#else
    asm("v_permlane16_swap_b32 %0, %1" : "+v"(a), "+v"(b));
    __builtin_amdgcn_sched_barrier(0);
#endif
}

// DUAL-chain D -> next-layer B-frags, stage-major across BOTH chains:
// 16 exp2, 16 add, 16 rcp, 16 mul -- 15 independent ops between any
// dependent pair.  R22 evidence: under a 64-reg cap the allocator
// SERIALIZED the chains (VGPR=32).  This round's (256,6) cap gives it
// room to keep both chains live and actually emit this interleave.
template <bool SILU>
__device__ __forceinline__ void pack_exchange16_dual(
    const f32x4v& D0A, const f32x4v& D1A,
    const f32x4v& D0B, const f32x4v& D1B,
    BU& ba, BU& bb) {
    float sA[8], sB[8];
    if (SILU) {
        float uA[8], uB[8];
#pragma unroll
        for (int r = 0; r < 4; ++r) { uA[r] = exp2_fast(-D0A[r]); uA[4 + r] = exp2_fast(-D1A[r]); }
#pragma unroll
        for (int r = 0; r < 4; ++r) { uB[r] = exp2_fast(-D0B[r]); uB[4 + r] = exp2_fast(-D1B[r]); }
#pragma unroll
        for (int r = 0; r < 8; ++r) { uA[r] = 1.0f + uA[r]; }
#pragma unroll
        for (int r = 0; r < 8; ++r) { uB[r] = 1.0f + uB[r]; }
#pragma unroll
        for (int r = 0; r < 8; ++r) { uA[r] = __builtin_amdgcn_rcpf(uA[r]); }
#pragma unroll
        for (int r = 0; r < 8; ++r) { uB[r] = __builtin_amdgcn_rcpf(uB[r]); }
#pragma unroll
        for (int r = 0; r < 4; ++r) { sA[r] = D0A[r] * uA[r]; sA[4 + r] = D1A[r] * uA[4 + r]; }
#pragma unroll
        for (int r = 0; r < 4; ++r) { sB[r] = D0B[r] * uB[r]; sB[4 + r] = D1B[r] * uB[4 + r]; }
    } else {
#pragma unroll
        for (int r = 0; r < 4; ++r) { sA[r] = D0A[r]; sA[4 + r] = D1A[r]; }
#pragma unroll
        for (int r = 0; r < 4; ++r) { sB[r] = D0B[r]; sB[4 + r] = D1B[r]; }
    }
    unsigned PA0 = pk2(sA[0], sA[1]);
    unsigned PA1 = pk2(sA[2], sA[3]);
    unsigned QA0 = pk2(sA[4], sA[5]);
    unsigned QA1 = pk2(sA[6], sA[7]);
    unsigned PB0 = pk2(sB[0], sB[1]);
    unsigned PB1 = pk2(sB[2], sB[3]);
    unsigned QB0 = pk2(sB[4], sB[5]);
    unsigned QB1 = pk2(sB[6], sB[7]);
    pswap32(PA0, QA0);
    pswap32(PA1, QA1);
    pswap32(PB0, QB0);
    pswap32(PB1, QB1);
    pswap16(PA0, QA0);
    pswap16(PA1, QA1);
    pswap16(PB0, QB0);
    pswap16(PB1, QB1);
    ba.u[0] = PA0; ba.u[1] = PA1; ba.u[2] = QA0; ba.u[3] = QA1;
    bb.u[0] = PB0; bb.u[1] = PB1; bb.u[2] = QB0; bb.u[3] = QB1;
}

// Bias C-operand (f32x4) for feat-half h: bias[stage][16h + 4g + r].
__device__ __forceinline__ f32x4v ld_bias4(const float* sbias, int stage, int h, int g) {
    float4 q = *(const float4*)&sbias[stage * 32 + 16 * h + 4 * g];
    f32x4v v = {q.x, q.y, q.z, q.w};
    return v;
}

__device__ __forceinline__ f16x8 ld_frag(const f16* sfrag, int f, int ln) {
    return *(const f16x8*)&sfrag[(f * 64 + ln) * 8];
}

// x -> B-frag: col=lane&15 = batch row, k=8g+e = input feat.
template <bool GUARD>
__device__ __forceinline__ BU load_x(const float* __restrict__ x, long rb,
                                     int c, int g, int nrows) {
    BU b;
    b.u[0] = 0; b.u[1] = 0; b.u[2] = 0; b.u[3] = 0;
    const long r = rb + c;
    if (!GUARD || r < nrows) {
        const float* xp = x + r * INDIM;
        if (g == 0) {
            float2 p0 = *(const float2*)(xp + 0);
            float2 p1 = *(const float2*)(xp + 2);
            float2 p2 = *(const float2*)(xp + 4);
            float2 p3 = *(const float2*)(xp + 6);
            b.u[0] = pk2(p0.x, p0.y);
            b.u[1] = pk2(p1.x, p1.y);
            b.u[2] = pk2(p2.x, p2.y);
            b.u[3] = pk2(p3.x, p3.y);
        } else if (g == 1) {
            float2 p4 = *(const float2*)(xp + 8);
            b.u[0] = pk2(p4.x, p4.y);
        }
    }
    return b;
}

// Head D (16x16): lane = batch c, out-feats 4g+r.
template <bool GUARD>
__device__ __forceinline__ void store_o(float* __restrict__ out, long rb,
                                        int c, int g, int nrows, const f32x4v& H) {
    const long r = rb + c;
    if (!GUARD || r < nrows) {
        float* op = out + r * INDIM;
        if (g == 0) {
            *(float2*)(op + 0) = make_float2(H[0], H[1]);
            *(float2*)(op + 2) = make_float2(H[2], H[3]);
        } else if (g == 1) {
            *(float2*)(op + 4) = make_float2(H[0], H[1]);
            *(float2*)(op + 6) = make_float2(H[2], H[3]);
        } else if (g == 2) {
            *(float2*)(op + 8) = make_float2(H[0], H[1]);
        }
    }
}

// ---------------------------------------------------------------------------
// Main: 16x16x32 MFMA pipeline, DUAL 16-row chains per wave, NT=2 pairs.
// R22's VGPR=32 proved the (256,8) cap made the allocator SERIALIZE the
// chains (dual state can't fit 32 regs) -- the ILP never existed in the
// emitted code.  Single change this round: __launch_bounds__(256,6)
// (~84-reg cap).  Measured occupancy at (256,8) was only ~61% (~5 waves)
// so the 6-wave ceiling costs nothing; the reg headroom lets both chains
// stay live and the stage-major interleave actually be emitted.
// ---------------------------------------------------------------------------
template <bool GUARD>
__global__ __launch_bounds__(256, 6) void fno_main(
    const float* __restrict__ x,
    const f16*  __restrict__ fragbuf,   // [11][64][8] f16
    const float* __restrict__ bias2,    // [6][32] f32
    float* __restrict__ out,
    int nrows) {

    __shared__ __align__(16) f16 sfrag[11 * 64 * 8];   // 11264 B
    __shared__ __align__(16) float sbias[6 * 32];      // 768 B

    {
        const int tid = threadIdx.x;
        uint4* dv = (uint4*)sfrag;
        const uint4* sv = (const uint4*)fragbuf;
#pragma unroll
        for (int i = 0; i < 3; ++i) {
            int idx = tid + i * 256;
            if (idx < 704) dv[idx] = sv[idx];
        }
        if (tid < 48) ((float4*)sbias)[tid] = ((const float4*)bias2)[tid];
    }
    __syncthreads();

    const int tid = threadIdx.x;
    const int w   = tid >> 6;
    const int ln  = tid & 63;
    const int c   = ln & 15;   // batch col
    const int g   = ln >> 4;   // k-group / D-row group

    const long base = (long)blockIdx.x * (4 * NT * 32) + (long)w * (NT * 32);

#pragma unroll
    for (int t = 0; t < NT; ++t) {
        const long rbA = base + (long)t * 32;
        const long rbB = rbA + 16;

        // ---- stem: shared A-frags, 4 MFMAs across both chains ----
        BU bxA = load_x<GUARD>(x, rbA, c, g, nrows);
        BU bxB = load_x<GUARD>(x, rbB, c, g, nrows);
        f16x8 as0 = ld_frag(sfrag, 8, ln);
        f16x8 as1 = ld_frag(sfrag, 9, ln);
        f32x4v cb0 = ld_bias4(sbias, 0, 0, g);
        f32x4v cb1 = ld_bias4(sbias, 0, 1, g);
        f32x4v D0A = __builtin_amdgcn_mfma_f32_16x16x32_f16(as0, bxA.v, cb0, 0, 0, 0);
        f32x4v D1A = __builtin_amdgcn_mfma_f32_16x16x32_f16(as1, bxA.v, cb1, 0, 0, 0);
        f32x4v D0B = __builtin_amdgcn_mfma_f32_16x16x32_f16(as0, bxB.v, cb0, 0, 0, 0);
        f32x4v D1B = __builtin_amdgcn_mfma_f32_16x16x32_f16(as1, bxB.v, cb1, 0, 0, 0);

        BU ba, bb;
        pack_exchange16_dual<false>(D0A, D1A, D0B, D1B, ba, bb);

        // ---- 4 fused layers: shared weights, 4 MFMAs, dual pack ----
#pragma unroll
        for (int l = 0; l < LAYERS; ++l) {
            f16x8 w0 = ld_frag(sfrag, 2 * l, ln);
            f16x8 w1 = ld_frag(sfrag, 2 * l + 1, ln);
            f32x4v bl0 = ld_bias4(sbias, 1 + l, 0, g);
            f32x4v bl1 = ld_bias4(sbias, 1 + l, 1, g);
            f32x4v t0A = __builtin_amdgcn_mfma_f32_16x16x32_f16(w0, ba.v, bl0, 0, 0, 0);
            f32x4v t1A = __builtin_amdgcn_mfma_f32_16x16x32_f16(w1, ba.v, bl1, 0, 0, 0);
            f32x4v t0B = __builtin_amdgcn_mfma_f32_16x16x32_f16(w0, bb.v, bl0, 0, 0, 0);
            f32x4v t1B = __builtin_amdgcn_mfma_f32_16x16x32_f16(w1, bb.v, bl1, 0, 0, 0);
            pack_exchange16_dual<true>(t0A, t1A, t0B, t1B, ba, bb);
        }

        // ---- head: ONE shared A-frag, 2 MFMAs ----
        f16x8 ah = ld_frag(sfrag, 10, ln);
        f32x4v ch = ld_bias4(sbias, 5, 0, g);
        f32x4v HA = __builtin_amdgcn_mfma_f32_16x16x32_f16(ah, ba.v, ch, 0, 0, 0);
        f32x4v HB = __builtin_amdgcn_mfma_f32_16x16x32_f16(ah, bb.v, ch, 0, 0, 0);

        store_o<GUARD>(out, rbA, c, g, nrows, HA);
        store_o<GUARD>(out, rbB, c, g, nrows, HB);
    }
}

extern "C" void kernel_launch(void* const* d_in, const int* in_sizes, int n_in,
                              void* d_out, int out_size, void* d_ws, size_t ws_size,
                              hipStream_t stream) {
    const float* x      = (const float*)d_in[0];
    const float* stemW  = (const float*)d_in[1];
    const float* stemB  = (const float*)d_in[2];
    const float* fno_wr = (const float*)d_in[3];
    const float* fno_wi = (const float*)d_in[4];
    const float* projW  = (const float*)d_in[5];
    const float* projB  = (const float*)d_in[6];
    const float* headW  = (const float*)d_in[7];
    const float* headB  = (const float*)d_in[8];
    float* out = (float*)d_out;

    f16*   frag  = (f16*)((char*)d_ws + WS_FRAG_OFF);
    float* bias2 = (float*)((char*)d_ws + WS_BIAS_OFF);

    const int nrows = in_sizes[0] / INDIM;

    fno_prep<<<LAYERS, 1024, 0, stream>>>(fno_wr, fno_wi, projW, stemW, headW,
                                          stemB, projB, headB, frag, bias2);

    const int rows_per_block = 4 * NT * 32;   // 256
    const int nblk = (nrows + rows_per_block - 1) / rows_per_block;
    if (nrows % rows_per_block == 0)
        fno_main<false><<<nblk, 256, 0, stream>>>(x, frag, bias2, out, nrows);
    else
        fno_main<true><<<nblk, 256, 0, stream>>>(x, frag, bias2, out, nrows);
}

// Round 24
// 49.925 us; speedup vs baseline: 1.0631x; 1.0631x over previous
//
#include <hip/hip_runtime.h>
#include <math.h>

#define INDIM 10
#define DIM 32
#define LAYERS 4
#define MODES 17

#define LOG2E 1.4426950408889634f
#define LN2   0.6931471805599453f

// d_ws layout:
//   [0, 11264)        : frag f16 [11][64][8]  (A-operand fragments, W^T form)
//   [11264, 12032)    : bias2 f32 [6][32]     (compact per-stage bias tables)
#define WS_FRAG_OFF 0
#define WS_BIAS_OFF 11264

typedef _Float16 f16;
typedef _Float16 f16x8 __attribute__((ext_vector_type(8)));
typedef float f32x16 __attribute__((ext_vector_type(16)));
typedef unsigned u32x2 __attribute__((ext_vector_type(2)));

union BU { f16x8 v; unsigned u[4]; };
union CU { f32x16 v; float4 q[4]; };

// ---------------------------------------------------------------------------
// FUSED prep, 2-phase (R16-verified):
//   phase 1: 544 threads compute y_o(n) = sum_m e^{-2pi i mn/32} w[m][o]
//            ONCE into LDS.
//   phase 2: each (n,j) thread does the 17-term o-sum from LDS broadcast.
// log2e folding verified R11: Wc[0]*=LOG2E, projB*=LOG2E, headW*=LN2.
// ---------------------------------------------------------------------------
__global__ void fno_prep(const float* __restrict__ wr,
                         const float* __restrict__ wi,
                         const float* __restrict__ projW,
                         const float* __restrict__ stemW,
                         const float* __restrict__ headW,
                         const float* __restrict__ stemB,
                         const float* __restrict__ projB,
                         const float* __restrict__ headB,
                         f16* __restrict__ frag,
                         float* __restrict__ bias2) {
    const int l  = blockIdx.x;
    const int tx = threadIdx.x;
    const int j  = tx & 31;   // output position n' (= frag column c)
    const int n  = tx >> 5;   // input position n  (= frag k)

    __shared__ float ct[32], st[32];
    __shared__ float sre[MODES][32], sim[MODES][32];
    if (tx < 32) {
        float ang = (2.0f * 3.14159265358979323846f / 32.0f) * (float)tx;
        ct[tx] = cosf(ang);
        st[tx] = sinf(ang);
    }
    __syncthreads();

    const float* lwr = wr + l * MODES * MODES;
    const float* lwi = wi + l * MODES * MODES;

    // ---- phase 1: y_o(n) once per (o,n) ----
    if (tx < MODES * 32) {
        const int o  = tx >> 5;
        const int nn = tx & 31;
        float re = 0.0f, im = 0.0f;
        for (int m = 0; m < MODES; ++m) {
            int t = (m * nn) & 31;
            float c = ct[t], s = st[t];
            float a = lwr[m * MODES + o];
            float b = lwi[m * MODES + o];
            re += c * a + s * b;
            im += c * b - s * a;
        }
        sre[o][nn] = re;
        sim[o][nn] = im;
    }
    __syncthreads();

    // ---- phase 2: o-sum from LDS (sre/sim broadcast across j-lanes) ----
    float acc = 0.0f;
    for (int o = 0; o < MODES; ++o) {
        int t2 = (o * j) & 31;
        float f = (o == 0 || o == 16) ? 1.0f : 2.0f;
        acc += f * (sre[o][n] * ct[t2] - sim[o][n] * st[t2]);
    }
    acc = acc * (1.0f / 32.0f) + projW[(l * DIM + n) * DIM + j];

    const float wscale = (l == 0) ? LOG2E : 1.0f;
    const int kc = n >> 4;
    const int G  = (n >> 3) & 1;
    const int e  = n & 7;
    const int ln = G * 32 + j;
    frag[((l * 2 + kc) * 64 + ln) * 8 + e] = (f16)(wscale * acc);

    if (l == 0) {
        if (tx < 64) {
            const int lnn = tx;
            const int c2  = lnn & 31;
            const int G2  = lnn >> 5;
#pragma unroll
            for (int ee = 0; ee < 8; ++ee) {
                int k = 8 * G2 + ee;
                frag[(8 * 64 + lnn) * 8 + ee] =
                    (f16)(k < INDIM ? stemW[k * DIM + c2] : 0.0f);
            }
#pragma unroll
            for (int kcc = 0; kcc < 2; ++kcc)
#pragma unroll
                for (int ee = 0; ee < 8; ++ee) {
                    int k = 16 * kcc + 8 * G2 + ee;
                    frag[((9 + kcc) * 64 + lnn) * 8 + ee] =
                        (f16)(c2 < INDIM ? LN2 * headW[k * INDIM + c2] : 0.0f);
                }
        }
        if (tx < 32) {
#pragma unroll
            for (int f = 0; f < 6; ++f) {
                float v;
                if (f == 0)      v = stemB[tx];
                else if (f <= 4) v = LOG2E * projB[(f - 1) * DIM + tx];
                else             v = (tx < INDIM) ? headB[tx] : 0.0f;
                bias2[f * 32 + tx] = v;
            }
        }
    }
}

__device__ __forceinline__ float exp2_fast(float x) {
#if __has_builtin(__builtin_amdgcn_exp2f)
    return __builtin_amdgcn_exp2f(x);
#else
    return exp2f(x);
#endif
}

__device__ __forceinline__ unsigned pk2(float a, float b) {
    auto h2 = __builtin_amdgcn_cvt_pkrtz(a, b);   // v_cvt_pkrtz_f16_f32
    return __builtin_bit_cast(unsigned, h2);
}

// Compiler-modeled lane<32 <-> lane>=32 exchange (round-8-verified correct).
__device__ __forceinline__ void pswap(unsigned& a, unsigned& b) {
#if __has_builtin(__builtin_amdgcn_permlane32_swap)
    u32x2 r = __builtin_amdgcn_permlane32_swap(a, b, false, false);
    a = r[0];
    b = r[1];
#else
    asm("v_permlane32_swap_b32 %0, %1" : "+v"(a), "+v"(b));
    __builtin_amdgcn_sched_barrier(0);
#endif
}

// Single-chain D -> next-layer B-fragments.  Silu in TWO half-blocks of 8
// (8 exp2 -> 8 add -> 8 rcp -> 8 mul): still 7 independent ops between any
// dependent pair (trans pipe stays fed), peak live regs stay low.
template <bool SILU>
__device__ __forceinline__ void pack_exchange(const f32x16& D, BU& b0, BU& b1) {
    unsigned q[8];
#pragma unroll
    for (int h = 0; h < 2; ++h) {
        float u[8];
        if (SILU) {
#pragma unroll
            for (int r = 0; r < 8; ++r) u[r] = exp2_fast(-D[8 * h + r]);
#pragma unroll
            for (int r = 0; r < 8; ++r) u[r] = 1.0f + u[r];
#pragma unroll
            for (int r = 0; r < 8; ++r) u[r] = __builtin_amdgcn_rcpf(u[r]);
#pragma unroll
            for (int r = 0; r < 8; ++r) u[r] = D[8 * h + r] * u[r];
        } else {
#pragma unroll
            for (int r = 0; r < 8; ++r) u[r] = D[8 * h + r];
        }
        q[4 * h + 0] = pk2(u[0], u[1]);
        q[4 * h + 1] = pk2(u[2], u[3]);
        q[4 * h + 2] = pk2(u[4], u[5]);
        q[4 * h + 3] = pk2(u[6], u[7]);
    }
    pswap(q[0], q[2]);
    pswap(q[1], q[3]);
    pswap(q[4], q[6]);
    pswap(q[5], q[7]);
    b0.u[0] = q[0]; b0.u[1] = q[1]; b0.u[2] = q[2]; b0.u[3] = q[3];
    b1.u[0] = q[4]; b1.u[1] = q[5]; b1.u[2] = q[6]; b1.u[3] = q[7];
}

// C-operand bias fragment from the LDS table (half-wave broadcast reads).
__device__ __forceinline__ f32x16 ld_bias(const float* sbias, int stage, int G) {
    CU c;
#pragma unroll
    for (int rq = 0; rq < 4; ++rq)
        c.q[rq] = *(const float4*)&sbias[stage * 32 + rq * 8 + G * 4];
    return c.v;
}

// A-operand fragment from LDS: lane ln reads its own 16B at stride 16
// (contiguous 1KB per frag -> conflict-free ds_read_b128; verified R14).
__device__ __forceinline__ f16x8 ld_frag(const f16* sfrag, int f, int ln) {
    return *(const f16x8*)&sfrag[(f * 64 + ln) * 8];
}

template <bool GUARD>
__device__ __forceinline__ BU load_x(const float* __restrict__ x, long rb,
                                     int c, int G, int nrows) {
    BU b;
    b.u[0] = 0; b.u[1] = 0; b.u[2] = 0; b.u[3] = 0;
    const long r = rb + c;
    if (!GUARD || r < nrows) {
        const float* xp = x + r * INDIM;
        if (G == 0) {
            float2 p0 = *(const float2*)(xp + 0);
            float2 p1 = *(const float2*)(xp + 2);
            float2 p2 = *(const float2*)(xp + 4);
            float2 p3 = *(const float2*)(xp + 6);
            b.u[0] = pk2(p0.x, p0.y);
            b.u[1] = pk2(p1.x, p1.y);
            b.u[2] = pk2(p2.x, p2.y);
            b.u[3] = pk2(p3.x, p3.y);
        } else {
            float2 p4 = *(const float2*)(xp + 8);
            b.u[0] = pk2(p4.x, p4.y);
        }
    }
    return b;
}

template <bool GUARD>
__device__ __forceinline__ void store_o(float* __restrict__ out, long rb,
                                        int c, int G, int nrows, const f32x16& Dh) {
    const long r = rb + c;
    if (!GUARD || r < nrows) {
        float* op = out + r * INDIM;
        if (G == 0) {
            *(float2*)(op + 0) = make_float2(Dh[0], Dh[1]);  // f0,f1
            *(float2*)(op + 2) = make_float2(Dh[2], Dh[3]);  // f2,f3
            *(float2*)(op + 8) = make_float2(Dh[4], Dh[5]);  // f8,f9
        } else {
            *(float2*)(op + 4) = make_float2(Dh[0], Dh[1]);  // f4,f5
            *(float2*)(op + 6) = make_float2(Dh[2], Dh[3]);  // f6,f7
        }
    }
}

// ---------------------------------------------------------------------------
// Main: transposed 32x32 MFMA pipeline, SINGLE 32-row chain per wave.
// BEST-MEASURED configuration of the session (R16: 50.29us total, kernel
// ~47us, VGPR 28, occ ~64%).  R17-R23 tested 16x16 tiles, NT granularity,
// dual-chain ILP, and reg-cap levers -- all landed at or above this.
// Weights in LDS (R14), bias at-use (R13), half-block stage-major silu,
// log2e fold (R11), 2-phase prep (R16).
// ---------------------------------------------------------------------------
template <bool GUARD>
__global__ __launch_bounds__(256, 8) void fno_main(
    const float* __restrict__ x,
    const f16*  __restrict__ fragbuf,   // [11][64][8] f16
    const float* __restrict__ bias2,    // [6][32] f32
    float* __restrict__ out,
    int nrows) {

    __shared__ __align__(16) f16 sfrag[11 * 64 * 8];   // 11264 B
    __shared__ __align__(16) float sbias[6 * 32];      // 768 B

    {
        const int tid = threadIdx.x;
        uint4* dv = (uint4*)sfrag;
        const uint4* sv = (const uint4*)fragbuf;
#pragma unroll
        for (int i = 0; i < 3; ++i) {
            int idx = tid + i * 256;
            if (idx < 704) dv[idx] = sv[idx];
        }
        if (tid < 48) ((float4*)sbias)[tid] = ((const float4*)bias2)[tid];
    }
    __syncthreads();

    const int tid = threadIdx.x;
    const int w   = tid >> 6;
    const int ln  = tid & 63;
    const int c   = ln & 31;
    const int G   = ln >> 5;

    const long rb = (long)blockIdx.x * 128 + (long)w * 32;

    // ---- stem ----
    BU bx = load_x<GUARD>(x, rb, c, G, nrows);
    f16x8 as = ld_frag(sfrag, 8, ln);
    f32x16 cb = ld_bias(sbias, 0, G);
    f32x16 D = __builtin_amdgcn_mfma_f32_32x32x16_f16(as, bx.v, cb, 0, 0, 0);

    BU b0, b1;
    pack_exchange<false>(D, b0, b1);

    // ---- 4 fused layers; weights + bias read from LDS at use ----
#pragma unroll
    for (int l = 0; l < LAYERS; ++l) {
        f16x8 w0 = ld_frag(sfrag, 2 * l, ln);
        f16x8 w1 = ld_frag(sfrag, 2 * l + 1, ln);
        cb = ld_bias(sbias, 1 + l, G);
        f32x16 t = __builtin_amdgcn_mfma_f32_32x32x16_f16(w0, b0.v, cb, 0, 0, 0);
        t = __builtin_amdgcn_mfma_f32_32x32x16_f16(w1, b1.v, t, 0, 0, 0);
        pack_exchange<true>(t, b0, b1);
    }

    // ---- head ----
    f16x8 ah0 = ld_frag(sfrag, 9, ln);
    f16x8 ah1 = ld_frag(sfrag, 10, ln);
    cb = ld_bias(sbias, 5, G);
    f32x16 H = __builtin_amdgcn_mfma_f32_32x32x16_f16(ah0, b0.v, cb, 0, 0, 0);
    H = __builtin_amdgcn_mfma_f32_32x32x16_f16(ah1, b1.v, H, 0, 0, 0);

    store_o<GUARD>(out, rb, c, G, nrows, H);
}

extern "C" void kernel_launch(void* const* d_in, const int* in_sizes, int n_in,
                              void* d_out, int out_size, void* d_ws, size_t ws_size,
                              hipStream_t stream) {
    const float* x      = (const float*)d_in[0];
    const float* stemW  = (const float*)d_in[1];
    const float* stemB  = (const float*)d_in[2];
    const float* fno_wr = (const float*)d_in[3];
    const float* fno_wi = (const float*)d_in[4];
    const float* projW  = (const float*)d_in[5];
    const float* projB  = (const float*)d_in[6];
    const float* headW  = (const float*)d_in[7];
    const float* headB  = (const float*)d_in[8];
    float* out = (float*)d_out;

    f16*   frag  = (f16*)((char*)d_ws + WS_FRAG_OFF);
    float* bias2 = (float*)((char*)d_ws + WS_BIAS_OFF);

    const int nrows = in_sizes[0] / INDIM;

    fno_prep<<<LAYERS, 1024, 0, stream>>>(fno_wr, fno_wi, projW, stemW, headW,
                                          stemB, projB, headB, frag, bias2);

    const int rows_per_block = 128;   // 4 waves x 1 chain x 32 rows
    const int nblk = (nrows + rows_per_block - 1) / rows_per_block;
    if (nrows % rows_per_block == 0)
        fno_main<false><<<nblk, 256, 0, stream>>>(x, frag, bias2, out, nrows);
    else
        fno_main<true><<<nblk, 256, 0, stream>>>(x, frag, bias2, out, nrows);
}